// Round 9
// baseline (383.269 us; speedup 1.0000x reference)
//
#include <hip/hip_runtime.h>
#include <hip/hip_bf16.h>

// ---------------------------------------------------------------------------
// HeteroGNN forward (round 21):
//   - GEMM: R20's inline-asm depth-4 pipeline, REPAIRED: all asm operands
//     are now true ext_vector types (f32x4, bf16x8) — HIP's float4 is a
//     struct/class and is not a valid "v"-constraint operand (R20's abort).
//     4 sets x 6 x global_load_dwordx4 = 24 outstanding/wave (24KB in
//     flight), counted s_waitcnt vmcnt(18) retires exactly the oldest set,
//     sched_barrier(0) fences each wait (guide rule 18); static literal
//     offsets (rule 20); bases advance 512B(A)/256B(B) per macro-iter.
//     Rationale (R12-R19): HBM rate == bytes-in-flight/900cy; barrier-staged
//     LDS duty-cycles to ~3KB/CU (1.6-1.9 TB/s); compiler collapses
//     non-asm register prefetch (VGPR tells 48/56). Asm loads cannot be
//     collapsed or re-scheduled.
//   - Operand math / epilogue identical to R15/R16 (harness-verified):
//     BM=32 BN=128, grid 1250, 4 waves, wave tile 32x32.
//   - prep / post_t / post_l unchanged (verified; rest ~228us invariant).
// ---------------------------------------------------------------------------

#define H 128
#define K_DIM 1280
#define LIG_IN 4
#define CAP_L 24    // max ligand degree (lambda=2.5; observed max ~13)
#define CAP_T 48    // max target degree (lambda=12.5; observed max ~34)

typedef __attribute__((ext_vector_type(8))) short bf16x8;
typedef __attribute__((ext_vector_type(4))) float f32x4;

// ---- fused prep: adjacency build + weight cast ----------------------------
__global__ void prep(const int* __restrict__ src, const int* __restrict__ dst,
                     int* __restrict__ cur_l, int* __restrict__ cur_t,
                     int* __restrict__ adje, int* __restrict__ adjs, int E, int nb_fill,
                     const float* __restrict__ Wl, const float* __restrict__ Wr,
                     __hip_bfloat16* __restrict__ Wt, int nw)
{
    int b = blockIdx.x;
    if (b < nb_fill) {
        int e = b * blockDim.x + threadIdx.x;
        if (e >= E) return;
        int s = src[e], d = dst[e];
        int p = atomicAdd(&cur_l[s], 1);
        adje[s * CAP_L + p] = e;
        int q = atomicAdd(&cur_t[d], 1);
        adjs[d * CAP_T + q] = s;
    } else {
        int idx = (b - nb_fill) * blockDim.x + threadIdx.x;
        if (idx >= nw) return;
        int nr = idx / K_DIM, k = idx - nr * K_DIM;
        float v = (nr < H) ? Wl[k * H + nr] : Wr[k * H + (nr - H)];
        Wt[idx] = __float2bfloat16(v);
    }
}

// ---- GEMM: [M,1280] f32 @ [1280,256] bf16 -> y_tl | t_lin (f32) -----------
__device__ inline bf16x8 cvt8v(f32x4 u, f32x4 v)
{
    union { __hip_bfloat16 h[8]; bf16x8 f; } r;
    r.h[0] = __float2bfloat16(u[0]); r.h[1] = __float2bfloat16(u[1]);
    r.h[2] = __float2bfloat16(u[2]); r.h[3] = __float2bfloat16(u[3]);
    r.h[4] = __float2bfloat16(v[0]); r.h[5] = __float2bfloat16(v[1]);
    r.h[6] = __float2bfloat16(v[2]); r.h[7] = __float2bfloat16(v[3]);
    return r.f;
}

// asm 16B load with literal immediate offset — backend cannot collapse these.
// dst MUST be an ext_vector type (f32x4 / bf16x8).
#define GL4(dst, ptr, OFF) \
    asm volatile("global_load_dwordx4 %0, %1, off offset:" #OFF \
                 : "=&v"(dst) : "v"(ptr) : "memory")

#define WAITV(N) do { \
    asm volatile("s_waitcnt vmcnt(" #N ")" ::: "memory"); \
    __builtin_amdgcn_sched_barrier(0); } while (0)

// one pipeline set: k-step of 32 (A row0 32B, A row1 32B, B col0/col1 16B)
#define DECL_SET(s) f32x4 u0##s, v0##s, u1##s, v1##s; bf16x8 p0##s, p1##s

// OA = rel_step*128, OA2 = OA+16 (A bytes); OB = rel_step*64 (B bytes)
#define LOAD_SET(s, OA, OA2, OB) do { \
    GL4(u0##s, pa0, OA); GL4(v0##s, pa0, OA2); \
    GL4(u1##s, pa1, OA); GL4(v1##s, pa1, OA2); \
    GL4(p0##s, pb0, OB); GL4(p1##s, pb1, OB); } while (0)

#define COMPUTE_SET(s) do { \
    bf16x8 A0_ = cvt8v(u0##s, v0##s); \
    bf16x8 A1_ = cvt8v(u1##s, v1##s); \
    acc00 = __builtin_amdgcn_mfma_f32_16x16x32_bf16(A0_, p0##s, acc00, 0, 0, 0); \
    acc01 = __builtin_amdgcn_mfma_f32_16x16x32_bf16(A0_, p1##s, acc01, 0, 0, 0); \
    acc10 = __builtin_amdgcn_mfma_f32_16x16x32_bf16(A1_, p0##s, acc10, 0, 0, 0); \
    acc11 = __builtin_amdgcn_mfma_f32_16x16x32_bf16(A1_, p1##s, acc11, 0, 0, 0); } while (0)

// block = 256 thr (4 waves), BM=32, BN=128 (nb in {0,1}); wave tile 32x32.
// MFMA 16x16x32 bf16: lane l supplies row/col = l&15, k = (l>>4)*8..+7.
__global__ __launch_bounds__(256)
void gemm_asm(const float* __restrict__ Xf,          // [M,1280] f32
              const unsigned short* __restrict__ Wt, // [256,1280] bf16 n-major
              float* __restrict__ y_tl, float* __restrict__ t_lin, int M)
{
    const int t = threadIdx.x;
    const int w = t >> 6, lane = t & 63;
    const int m16 = lane & 15, q = lane >> 4;      // q in 0..3
    const int mb = blockIdx.x >> 1, nb = blockIdx.x & 1;
    const int bm = mb * 32;
    const int col0 = nb * 128 + w * 32;            // wave's first output col

    const int r0 = min(bm + m16,      M - 1);
    const int r1 = min(bm + m16 + 16, M - 1);
    const float* pa0 = Xf + (size_t)r0 * K_DIM + q * 8;
    const float* pa1 = Xf + (size_t)r1 * K_DIM + q * 8;
    const unsigned short* pb0 = Wt + (size_t)(col0 + m16)      * K_DIM + q * 8;
    const unsigned short* pb1 = Wt + (size_t)(col0 + m16 + 16) * K_DIM + q * 8;

    f32x4 acc00 = (f32x4){0.f, 0.f, 0.f, 0.f};
    f32x4 acc01 = (f32x4){0.f, 0.f, 0.f, 0.f};
    f32x4 acc10 = (f32x4){0.f, 0.f, 0.f, 0.f};
    f32x4 acc11 = (f32x4){0.f, 0.f, 0.f, 0.f};

    DECL_SET(0); DECL_SET(1); DECL_SET(2); DECL_SET(3);

    // prologue: abs k-steps 0..3 in flight (24 loads outstanding)
    LOAD_SET(0,   0,  16,   0);
    LOAD_SET(1, 128, 144,  64);
    LOAD_SET(2, 256, 272, 128);
    LOAD_SET(3, 384, 400, 192);

    // 9 macro-iters: iter m computes abs steps 4m..4m+3, loads 4m+4..4m+7
    for (int m = 0; m < 9; ++m) {
        WAITV(18); COMPUTE_SET(0); LOAD_SET(0, 512, 528, 256);
        WAITV(18); COMPUTE_SET(1); LOAD_SET(1, 640, 656, 320);
        WAITV(18); COMPUTE_SET(2); LOAD_SET(2, 768, 784, 384);
        WAITV(18); COMPUTE_SET(3); LOAD_SET(3, 896, 912, 448);
        pa0 += 128; pa1 += 128;   // 4 k-steps = 512 B of f32
        pb0 += 128; pb1 += 128;   // 4 k-steps = 256 B of bf16
    }
    // epilogue: abs steps 36..39 already in flight
    WAITV(18); COMPUTE_SET(0);
    WAITV(12); COMPUTE_SET(1);
    WAITV(6);  COMPUTE_SET(2);
    WAITV(0);  COMPUTE_SET(3);

    // epilogue: row = bm + i*16 + q*4 + r; col(local) = w*32 + j*16 + m16
    float* __restrict__ Y = nb ? t_lin : y_tl;
#pragma unroll
    for (int r = 0; r < 4; ++r) {
        int row0 = bm + q * 4 + r;
        int row1 = row0 + 16;
        if (row0 < M) {
            Y[(size_t)row0 * H + w * 32 + m16]      = acc00[r];
            Y[(size_t)row0 * H + w * 32 + 16 + m16] = acc01[r];
        }
        if (row1 < M) {
            Y[(size_t)row1 * H + w * 32 + m16]      = acc10[r];
            Y[(size_t)row1 * H + w * 32 + 16 + m16] = acc11[r];
        }
    }
}

// ---- target post (wave per target): gather agg + linear + relu + dot ------
__global__ void post_t(const int* __restrict__ cur_t, const int* __restrict__ adjs,
                       const float* __restrict__ xl, const float* __restrict__ t_lin,
                       const float* __restrict__ W_lt_l, const float* __restrict__ b_lt_l,
                       const float* __restrict__ W_ep, const float* __restrict__ b_ep,
                       float* __restrict__ st, int NT)
{
    int wid = (blockIdx.x * blockDim.x + threadIdx.x) >> 6;
    int lane = threadIdx.x & 63;
    if (wid >= NT) return;
    int cnt = cur_t[wid];
    float a0 = 0.f, a1 = 0.f, a2 = 0.f, a3 = 0.f;
    for (int j = lane; j < cnt; j += 64) {
        int s = adjs[wid * CAP_T + j];
        float4 v = *(const float4*)(xl + (size_t)s * LIG_IN);
        a0 += v.x; a1 += v.y; a2 += v.z; a3 += v.w;
    }
#pragma unroll
    for (int off = 32; off > 0; off >>= 1) {
        a0 += __shfl_xor(a0, off);
        a1 += __shfl_xor(a1, off);
        a2 += __shfl_xor(a2, off);
        a3 += __shfl_xor(a3, off);
    }
    float inv = 1.0f / fmaxf((float)cnt, 1.0f);
    a0 *= inv; a1 *= inv; a2 *= inv; a3 *= inv;
    float acc = 0.f;
#pragma unroll
    for (int p = 0; p < 2; ++p) {
        int h = lane + p * 64;
        float v = a0 * W_lt_l[h] + a1 * W_lt_l[H + h] + a2 * W_lt_l[2 * H + h] +
                  a3 * W_lt_l[3 * H + h] + b_lt_l[h] + t_lin[(size_t)wid * H + h];
        v = fmaxf(v, 0.f);
        acc += v * W_ep[H + h];
    }
#pragma unroll
    for (int off = 32; off > 0; off >>= 1) acc += __shfl_down(acc, off);
    if (lane == 0) st[wid] = acc + b_ep[0];
}

// ---- ligand post + edge write (wave per ligand) ---------------------------
__global__ void post_l(const int* __restrict__ cur_l, const int* __restrict__ adje,
                       const int* __restrict__ edge_dst,
                       const float* __restrict__ y_tl, const float* __restrict__ xl,
                       const float* __restrict__ W_tl_r, const float* __restrict__ b_tl_l,
                       const float* __restrict__ W_ep, const float* __restrict__ st,
                       float* __restrict__ out, int NL)
{
    int wid = (blockIdx.x * blockDim.x + threadIdx.x) >> 6;
    int lane = threadIdx.x & 63;
    if (wid >= NL) return;
    int cnt = cur_l[wid];
    int e = 0, d = 0;
    if (lane < cnt) {
        e = adje[wid * CAP_L + lane];   // coalesced
        d = edge_dst[e];                // one gather instr for the wave
    }
    float a0 = 0.f, a1 = 0.f;   // h = 2*lane, 2*lane+1
    for (int j = 0; j < cnt; ++j) {
        int dj = __shfl(d, j);
        float2 f = ((const float2*)(y_tl + (size_t)dj * H))[lane];  // 512B row load
        a0 += f.x;
        a1 += f.y;
    }
    float inv = 1.0f / fmaxf((float)cnt, 1.0f);
    float4 x = *(const float4*)(xl + (size_t)wid * LIG_IN);
    float acc = 0.f;
    {
        int h = 2 * lane;
        float v = a0 * inv + b_tl_l[h] +
                  x.x * W_tl_r[h] + x.y * W_tl_r[H + h] +
                  x.z * W_tl_r[2 * H + h] + x.w * W_tl_r[3 * H + h];
        v = fmaxf(v, 0.f);
        acc += v * W_ep[h];
    }
    {
        int h = 2 * lane + 1;
        float v = a1 * inv + b_tl_l[h] +
                  x.x * W_tl_r[h] + x.y * W_tl_r[H + h] +
                  x.z * W_tl_r[2 * H + h] + x.w * W_tl_r[3 * H + h];
        v = fmaxf(v, 0.f);
        acc += v * W_ep[h];
    }
#pragma unroll
    for (int off = 32; off > 0; off >>= 1) acc += __shfl_xor(acc, off);  // all lanes
    if (lane < cnt) out[e] = acc + st[d];
}

// ---------------------------------------------------------------------------
extern "C" void kernel_launch(void* const* d_in, const int* in_sizes, int n_in,
                              void* d_out, int out_size, void* d_ws, size_t ws_size,
                              hipStream_t stream) {
    const float* x_ligand = (const float*)d_in[0];
    const float* x_target = (const float*)d_in[1];
    const int*   edge_src = (const int*)d_in[2];
    const int*   edge_dst = (const int*)d_in[3];
    const float* W_lt_l   = (const float*)d_in[4];
    const float* b_lt_l   = (const float*)d_in[5];
    const float* W_lt_r   = (const float*)d_in[6];
    const float* W_tl_l   = (const float*)d_in[7];
    const float* b_tl_l   = (const float*)d_in[8];
    const float* W_tl_r   = (const float*)d_in[9];
    const float* W_ep     = (const float*)d_in[10];
    const float* b_ep     = (const float*)d_in[11];
    float* out = (float*)d_out;

    const int NL = in_sizes[0] / LIG_IN;   // 100000
    const int NT = in_sizes[1] / K_DIM;    // 20000
    const int E  = in_sizes[2];            // 250000

    // ---- workspace layout (16B-aligned offsets) ----
    char* ws = (char*)d_ws;
    size_t off = 0;
    auto take = [&](size_t bytes) { size_t o = off; off += (bytes + 15) & ~(size_t)15; return o; };
    size_t off_Wt     = take((size_t)2 * H * K_DIM * 2); // 655 KB bf16
    size_t off_y_tl   = take((size_t)NT * H * 4);        // 10.24 MB
    size_t off_t_lin  = take((size_t)NT * H * 4);        // 10.24 MB
    size_t off_adje   = take((size_t)NL * CAP_L * 4);    // 9.6 MB
    size_t off_adjs   = take((size_t)NT * CAP_T * 4);    // 3.84 MB
    size_t off_cur_l  = take((size_t)NL * 4);            // <- memset start
    size_t off_cur_t  = take((size_t)NT * 4);            // <- memset end
    size_t off_st     = take((size_t)NT * 4);
    if (off > ws_size) {
        hipMemsetAsync(d_out, 0, (size_t)out_size * 4, stream);
        return;
    }

    __hip_bfloat16* Wt = (__hip_bfloat16*)(ws + off_Wt);
    float* y_tl  = (float*)(ws + off_y_tl);
    float* t_lin = (float*)(ws + off_t_lin);
    int*   adje  = (int*)(ws + off_adje);
    int*   adjs  = (int*)(ws + off_adjs);
    int*   cur_l = (int*)(ws + off_cur_l);
    int*   cur_t = (int*)(ws + off_cur_t);
    float* st    = (float*)(ws + off_st);

    // zero the cursors (contiguous)
    hipMemsetAsync(cur_l, 0, off_st - off_cur_l, stream);

    // 1. fused adjacency build + weight cast
    int nw = 2 * H * K_DIM;
    int nb_fill = (E + 255) / 256;
    int nb_cast = (nw + 255) / 256;
    prep<<<nb_fill + nb_cast, 256, 0, stream>>>(edge_src, edge_dst, cur_l, cur_t,
                                                adje, adjs, E, nb_fill,
                                                W_tl_l, W_lt_r, Wt, nw);

    // 2. GEMM: asm-pipelined direct streaming; grid 1250 (mb=bid>>1, nb=bid&1)
    gemm_asm<<<((NT + 31) / 32) * 2, 256, 0, stream>>>(x_target, (const unsigned short*)Wt,
                                                       y_tl, t_lin, NT);

    // 3. target post -> st (+ b_ep folded)
    post_t<<<(NT * 64 + 255) / 256, 256, 0, stream>>>(cur_t, adjs, x_ligand, t_lin,
                                                      W_lt_l, b_lt_l, W_ep, b_ep, st, NT);

    // 4. ligand post + edge write -> out
    post_l<<<(NL * 64 + 255) / 256, 256, 0, stream>>>(cur_l, adje, edge_dst, y_tl, x_ligand,
                                                      W_tl_r, b_tl_l, W_ep, st, out, NL);
}

// Round 10
// 302.025 us; speedup vs baseline: 1.2690x; 1.2690x over previous
//
#include <hip/hip_runtime.h>
#include <hip/hip_bf16.h>

// ---------------------------------------------------------------------------
// HeteroGNN forward (round 22 — FINAL, revert to verified best R16):
//   - GEMM: R12-verified single-buffer LDS DMA staging (best of 7 measured
//     structures; 67-73us, ~1.75 TB/s effective). BM=64 BN=128 BK=64,
//     grid 626, A slot16B = m*16+(c^(m&15)) [f32], B slot = n*8+(c^(n&7))
//     [bf16]; all ds_read_b128 patterns 2-way (free).
//     Search record: barrier-staged variants (dbuf+counted-vmcnt, hi-TLP,
//     BK=128, stage-A-once) 67-131us; register-streaming (compiler-sched,
//     named-set, inline-asm depth-4) all collapse to depth-1 (VGPR tells
//     48/56/68 — SIInsertWaitcnts drains vmcnt before consuming asm
//     outputs) at ~158us. ~1.75 TB/s is the HIP-source floor here.
//   - Non-GEMM: 4 dispatches (prep = fill+cast; post_t; post_l with edge
//     write fused — edge_out pass deleted); rest ~226us invariant across
//     4 structural rewrites (dispatch/harness-dominated).
// ---------------------------------------------------------------------------

#define H 128
#define K_DIM 1280
#define LIG_IN 4
#define CAP_L 24    // max ligand degree (lambda=2.5; observed max ~13)
#define CAP_T 48    // max target degree (lambda=12.5; observed max ~34)
#define NCH 20      // K_DIM / 64

typedef __attribute__((ext_vector_type(8))) short bf16x8;
typedef __attribute__((ext_vector_type(4))) float f32x4;

#define AS1(p) ((const __attribute__((address_space(1))) void*)(p))
#define AS3(p) ((__attribute__((address_space(3))) void*)(p))

// ---- fused prep: adjacency build + weight cast ----------------------------
// ligand side stores EDGE ID (post_l derives dst via edge_dst[e]);
// target side stores SRC ID (post_t gathers x_ligand rows).
__global__ void prep(const int* __restrict__ src, const int* __restrict__ dst,
                     int* __restrict__ cur_l, int* __restrict__ cur_t,
                     int* __restrict__ adje, int* __restrict__ adjs, int E, int nb_fill,
                     const float* __restrict__ Wl, const float* __restrict__ Wr,
                     __hip_bfloat16* __restrict__ Wt, int nw)
{
    int b = blockIdx.x;
    if (b < nb_fill) {
        int e = b * blockDim.x + threadIdx.x;
        if (e >= E) return;
        int s = src[e], d = dst[e];
        int p = atomicAdd(&cur_l[s], 1);
        adje[s * CAP_L + p] = e;
        int q = atomicAdd(&cur_t[d], 1);
        adjs[d * CAP_T + q] = s;
    } else {
        int idx = (b - nb_fill) * blockDim.x + threadIdx.x;
        if (idx >= nw) return;
        int nr = idx / K_DIM, k = idx - nr * K_DIM;
        float v = (nr < H) ? Wl[k * H + nr] : Wr[k * H + (nr - H)];
        Wt[idx] = __float2bfloat16(v);
    }
}

// ---- GEMM: [M,1280] f32 @ [1280,256] bf16 -> y_tl | t_lin (f32) -----------
__device__ inline bf16x8 cvt8(float4 u, float4 v)
{
    union { __hip_bfloat16 h[8]; bf16x8 f; } r;
    r.h[0] = __float2bfloat16(u.x); r.h[1] = __float2bfloat16(u.y);
    r.h[2] = __float2bfloat16(u.z); r.h[3] = __float2bfloat16(u.w);
    r.h[4] = __float2bfloat16(v.x); r.h[5] = __float2bfloat16(v.y);
    r.h[6] = __float2bfloat16(v.z); r.h[7] = __float2bfloat16(v.w);
    return r.f;
}

__global__ __launch_bounds__(256)
void gemm_fused(const float* __restrict__ Xf,          // [M,1280] f32
                const unsigned short* __restrict__ Wt, // [256,1280] bf16 n-major
                float* __restrict__ y_tl, float* __restrict__ t_lin, int M)
{
    __shared__ float As[64 * 64];   // 16 KB; 16B-slot = m*16 + (c ^ (m&15))
    __shared__ short Bs[128 * 64];  // 16 KB; 16B-slot = n*8 + (c ^ (n&7))

    const int t = threadIdx.x;
    const int w = t >> 6, lane = t & 63;
    const int m16 = lane & 15, q = lane >> 4;
    const int wm = w & 1, wn = w >> 1;          // 2x2 wave grid
    const int mb = blockIdx.x >> 1, nb = blockIdx.x & 1;
    const int bm = mb * 64;
    const int nb128 = nb * 128;

    // ---- staging address setup (per-lane swizzled global source) ----
    // A: 1024 slots (64 rows x 16 chunks of 16B); 4 DMA instrs/wave/chunk
    const float* a_g[4];
#pragma unroll
    for (int i = 0; i < 4; ++i) {
        int slot = i * 256 + w * 64 + lane;
        int m = slot >> 4, cl = slot & 15;
        int cg = cl ^ (m & 15);
        int row = min(bm + m, M - 1);
        a_g[i] = Xf + (size_t)row * K_DIM + cg * 4;
    }
    // B: 1024 slots (128 rows x 8 chunks of 16B)
    const unsigned short* b_g[4];
#pragma unroll
    for (int i = 0; i < 4; ++i) {
        int slot = i * 256 + w * 64 + lane;
        int n = slot >> 3, cl = slot & 7;
        int cg = cl ^ (n & 7);
        b_g[i] = Wt + (size_t)(nb128 + n) * K_DIM + cg * 8;
    }

    f32x4 acc[2][4];
#pragma unroll
    for (int i = 0; i < 2; ++i)
#pragma unroll
        for (int j = 0; j < 4; ++j)
            acc[i][j] = (f32x4){0.f, 0.f, 0.f, 0.f};

    // ---- stage chunk 0 ----
#pragma unroll
    for (int i = 0; i < 4; ++i)
        __builtin_amdgcn_global_load_lds(AS1(a_g[i]), AS3((char*)As + (i * 256 + w * 64) * 16), 16, 0, 0);
#pragma unroll
    for (int i = 0; i < 4; ++i)
        __builtin_amdgcn_global_load_lds(AS1(b_g[i]), AS3((char*)Bs + (i * 256 + w * 64) * 16), 16, 0, 0);
    __syncthreads();

    for (int ch = 0; ch < NCH; ++ch) {
        // compute chunk ch (2 k-steps of 32)
#pragma unroll
        for (int ks = 0; ks < 2; ++ks) {
            bf16x8 aF[2];
#pragma unroll
            for (int i = 0; i < 2; ++i) {
                int row = wm * 32 + i * 16 + m16;
                int c = ks * 8 + q * 2;
                int s0 = row * 16 + (c ^ m16);        // row&15 == m16
                int s1 = s0 ^ 1;                      // chunk c|1
                float4 u = *(const float4*)((const char*)As + s0 * 16);
                float4 v = *(const float4*)((const char*)As + s1 * 16);
                aF[i] = cvt8(u, v);
            }
            bf16x8 bF[4];
#pragma unroll
            for (int j = 0; j < 4; ++j) {
                int n = wn * 64 + j * 16 + m16;
                int c = ks * 4 + q;
                int s = n * 8 + (c ^ (n & 7));
                bF[j] = *(const bf16x8*)((const char*)Bs + s * 16);
            }
#pragma unroll
            for (int i = 0; i < 2; ++i)
#pragma unroll
                for (int j = 0; j < 4; ++j)
                    acc[i][j] = __builtin_amdgcn_mfma_f32_16x16x32_bf16(aF[i], bF[j], acc[i][j], 0, 0, 0);
        }
        __syncthreads();                    // done reading chunk ch
        if (ch + 1 < NCH) {
            const int kc = (ch + 1) * 64;   // offset in elements (f32 / bf16)
#pragma unroll
            for (int i = 0; i < 4; ++i)
                __builtin_amdgcn_global_load_lds(AS1(a_g[i] + kc),
                                                 AS3((char*)As + (i * 256 + w * 64) * 16), 16, 0, 0);
#pragma unroll
            for (int i = 0; i < 4; ++i)
                __builtin_amdgcn_global_load_lds(AS1(b_g[i] + kc),
                                                 AS3((char*)Bs + (i * 256 + w * 64) * 16), 16, 0, 0);
            __syncthreads();                // publish chunk ch+1
        }
    }

    // ---- epilogue: row = bm + wm*32 + i*16 + q*4 + r; col = wn*64 + j*16 + m16
    float* __restrict__ Y = nb ? t_lin : y_tl;
#pragma unroll
    for (int i = 0; i < 2; ++i) {
#pragma unroll
        for (int j = 0; j < 4; ++j) {
            int col = wn * 64 + j * 16 + m16;
#pragma unroll
            for (int r = 0; r < 4; ++r) {
                int row = bm + wm * 32 + i * 16 + q * 4 + r;
                if (row < M) Y[(size_t)row * H + col] = acc[i][j][r];
            }
        }
    }
}

// ---- target post (wave per target): gather agg + linear + relu + dot ------
// st[wid] gets b_ep folded in so post_l's edge write is just sl + st[d].
__global__ void post_t(const int* __restrict__ cur_t, const int* __restrict__ adjs,
                       const float* __restrict__ xl, const float* __restrict__ t_lin,
                       const float* __restrict__ W_lt_l, const float* __restrict__ b_lt_l,
                       const float* __restrict__ W_ep, const float* __restrict__ b_ep,
                       float* __restrict__ st, int NT)
{
    int wid = (blockIdx.x * blockDim.x + threadIdx.x) >> 6;
    int lane = threadIdx.x & 63;
    if (wid >= NT) return;
    int cnt = cur_t[wid];
    float a0 = 0.f, a1 = 0.f, a2 = 0.f, a3 = 0.f;
    for (int j = lane; j < cnt; j += 64) {
        int s = adjs[wid * CAP_T + j];
        float4 v = *(const float4*)(xl + (size_t)s * LIG_IN);
        a0 += v.x; a1 += v.y; a2 += v.z; a3 += v.w;
    }
#pragma unroll
    for (int off = 32; off > 0; off >>= 1) {
        a0 += __shfl_xor(a0, off);
        a1 += __shfl_xor(a1, off);
        a2 += __shfl_xor(a2, off);
        a3 += __shfl_xor(a3, off);
    }
    float inv = 1.0f / fmaxf((float)cnt, 1.0f);
    a0 *= inv; a1 *= inv; a2 *= inv; a3 *= inv;
    float acc = 0.f;
#pragma unroll
    for (int p = 0; p < 2; ++p) {
        int h = lane + p * 64;
        float v = a0 * W_lt_l[h] + a1 * W_lt_l[H + h] + a2 * W_lt_l[2 * H + h] +
                  a3 * W_lt_l[3 * H + h] + b_lt_l[h] + t_lin[(size_t)wid * H + h];
        v = fmaxf(v, 0.f);
        acc += v * W_ep[H + h];
    }
#pragma unroll
    for (int off = 32; off > 0; off >>= 1) acc += __shfl_down(acc, off);
    if (lane == 0) st[wid] = acc + b_ep[0];
}

// ---- ligand post + edge write (wave per ligand) ---------------------------
// adje holds edge ids; lane-parallel prefetch of (e, d=edge_dst[e]); the
// gather loop is shfl + one 512B y_tl row load; after the all-lane reduce,
// lane j<cnt writes out[e_j] = sl + st[d_j].
__global__ void post_l(const int* __restrict__ cur_l, const int* __restrict__ adje,
                       const int* __restrict__ edge_dst,
                       const float* __restrict__ y_tl, const float* __restrict__ xl,
                       const float* __restrict__ W_tl_r, const float* __restrict__ b_tl_l,
                       const float* __restrict__ W_ep, const float* __restrict__ st,
                       float* __restrict__ out, int NL)
{
    int wid = (blockIdx.x * blockDim.x + threadIdx.x) >> 6;
    int lane = threadIdx.x & 63;
    if (wid >= NL) return;
    int cnt = cur_l[wid];
    int e = 0, d = 0;
    if (lane < cnt) {
        e = adje[wid * CAP_L + lane];   // coalesced
        d = edge_dst[e];                // one gather instr for the wave
    }
    float a0 = 0.f, a1 = 0.f;   // h = 2*lane, 2*lane+1
    for (int j = 0; j < cnt; ++j) {
        int dj = __shfl(d, j);
        float2 f = ((const float2*)(y_tl + (size_t)dj * H))[lane];  // 512B row load
        a0 += f.x;
        a1 += f.y;
    }
    float inv = 1.0f / fmaxf((float)cnt, 1.0f);
    float4 x = *(const float4*)(xl + (size_t)wid * LIG_IN);
    float acc = 0.f;
    {
        int h = 2 * lane;
        float v = a0 * inv + b_tl_l[h] +
                  x.x * W_tl_r[h] + x.y * W_tl_r[H + h] +
                  x.z * W_tl_r[2 * H + h] + x.w * W_tl_r[3 * H + h];
        v = fmaxf(v, 0.f);
        acc += v * W_ep[h];
    }
    {
        int h = 2 * lane + 1;
        float v = a1 * inv + b_tl_l[h] +
                  x.x * W_tl_r[h] + x.y * W_tl_r[H + h] +
                  x.z * W_tl_r[2 * H + h] + x.w * W_tl_r[3 * H + h];
        v = fmaxf(v, 0.f);
        acc += v * W_ep[h];
    }
#pragma unroll
    for (int off = 32; off > 0; off >>= 1) acc += __shfl_xor(acc, off);  // all lanes
    if (lane < cnt) out[e] = acc + st[d];
}

// ---------------------------------------------------------------------------
extern "C" void kernel_launch(void* const* d_in, const int* in_sizes, int n_in,
                              void* d_out, int out_size, void* d_ws, size_t ws_size,
                              hipStream_t stream) {
    const float* x_ligand = (const float*)d_in[0];
    const float* x_target = (const float*)d_in[1];
    const int*   edge_src = (const int*)d_in[2];
    const int*   edge_dst = (const int*)d_in[3];
    const float* W_lt_l   = (const float*)d_in[4];
    const float* b_lt_l   = (const float*)d_in[5];
    const float* W_lt_r   = (const float*)d_in[6];
    const float* W_tl_l   = (const float*)d_in[7];
    const float* b_tl_l   = (const float*)d_in[8];
    const float* W_tl_r   = (const float*)d_in[9];
    const float* W_ep     = (const float*)d_in[10];
    const float* b_ep     = (const float*)d_in[11];
    float* out = (float*)d_out;

    const int NL = in_sizes[0] / LIG_IN;   // 100000
    const int NT = in_sizes[1] / K_DIM;    // 20000
    const int E  = in_sizes[2];            // 250000

    // ---- workspace layout (16B-aligned offsets) ----
    char* ws = (char*)d_ws;
    size_t off = 0;
    auto take = [&](size_t bytes) { size_t o = off; off += (bytes + 15) & ~(size_t)15; return o; };
    size_t off_Wt     = take((size_t)2 * H * K_DIM * 2); // 655 KB bf16
    size_t off_y_tl   = take((size_t)NT * H * 4);        // 10.24 MB
    size_t off_t_lin  = take((size_t)NT * H * 4);        // 10.24 MB
    size_t off_adje   = take((size_t)NL * CAP_L * 4);    // 9.6 MB
    size_t off_adjs   = take((size_t)NT * CAP_T * 4);    // 3.84 MB
    size_t off_cur_l  = take((size_t)NL * 4);            // <- memset start
    size_t off_cur_t  = take((size_t)NT * 4);            // <- memset end
    size_t off_st     = take((size_t)NT * 4);
    if (off > ws_size) {
        hipMemsetAsync(d_out, 0, (size_t)out_size * 4, stream);
        return;
    }

    __hip_bfloat16* Wt = (__hip_bfloat16*)(ws + off_Wt);
    float* y_tl  = (float*)(ws + off_y_tl);
    float* t_lin = (float*)(ws + off_t_lin);
    int*   adje  = (int*)(ws + off_adje);
    int*   adjs  = (int*)(ws + off_adjs);
    int*   cur_l = (int*)(ws + off_cur_l);
    int*   cur_t = (int*)(ws + off_cur_t);
    float* st    = (float*)(ws + off_st);

    // zero the cursors (contiguous)
    hipMemsetAsync(cur_l, 0, off_st - off_cur_l, stream);

    // 1. fused adjacency build + weight cast
    int nw = 2 * H * K_DIM;
    int nb_fill = (E + 255) / 256;
    int nb_cast = (nw + 255) / 256;
    prep<<<nb_fill + nb_cast, 256, 0, stream>>>(edge_src, edge_dst, cur_l, cur_t,
                                                adje, adjs, E, nb_fill,
                                                W_tl_l, W_lt_r, Wt, nw);

    // 2. GEMM: grid 626 (mb = bid>>1, nb = bid&1) — R12-verified structure
    gemm_fused<<<((NT + 63) / 64) * 2, 256, 0, stream>>>(x_target, (const unsigned short*)Wt,
                                                         y_tl, t_lin, NT);

    // 3. target post -> st (+ b_ep folded)
    post_t<<<(NT * 64 + 255) / 256, 256, 0, stream>>>(cur_t, adjs, x_ligand, t_lin,
                                                      W_lt_l, b_lt_l, W_ep, b_ep, st, NT);

    // 4. ligand post + edge write -> out
    post_l<<<(NL * 64 + 255) / 256, 256, 0, stream>>>(cur_l, adje, edge_dst, y_tl, x_ligand,
                                                      W_tl_r, b_tl_l, W_ep, st, out, NL);
}

// Round 11
// 295.205 us; speedup vs baseline: 1.2983x; 1.0231x over previous
//
#include <hip/hip_runtime.h>
#include <hip/hip_bf16.h>

// ---------------------------------------------------------------------------
// HeteroGNN forward (round 23):
//   - NEW: x_target pre-cast f32->bf16 fused into prep (grid-stride
//     streaming, 153MB moved at copy-class BW). GEMM A-path now bf16:
//     staged A bytes halved (2 DMA/wave/chunk), cvt8 removed from the
//     inner loop (1 ds_read_b128 per A fragment), LDS 32->24KB, and the
//     51MB bf16 A is L3-resident when the GEMM stages it (the drain's
//     latency source drops from ~900cy HBM to L3). Theory: R12's 9 B/cy/CU
//     staging rate vs m97's 22.8 with L2-hot sources == latency-bound
//     drains; halve bytes + warm source.
//   - GEMM otherwise byte-identical to the R12-verified structure:
//     BM=64 BN=128 BK=64, grid 626, single-buffer, __syncthreads pairs.
//     A slot16B = m*8+(c^(m&7)) [bf16], B slot = n*8+(c^(n&7)) [bf16].
//   - post_t / post_l unchanged (verified).
// ---------------------------------------------------------------------------

#define H 128
#define K_DIM 1280
#define LIG_IN 4
#define CAP_L 24    // max ligand degree (lambda=2.5; observed max ~13)
#define CAP_T 48    // max target degree (lambda=12.5; observed max ~34)
#define NCH 20      // K_DIM / 64

typedef __attribute__((ext_vector_type(8))) short bf16x8;
typedef __attribute__((ext_vector_type(4))) float f32x4;

#define AS1(p) ((const __attribute__((address_space(1))) void*)(p))
#define AS3(p) ((__attribute__((address_space(3))) void*)(p))

__device__ inline bf16x8 cvt8(float4 u, float4 v)
{
    union { __hip_bfloat16 h[8]; bf16x8 f; } r;
    r.h[0] = __float2bfloat16(u.x); r.h[1] = __float2bfloat16(u.y);
    r.h[2] = __float2bfloat16(u.z); r.h[3] = __float2bfloat16(u.w);
    r.h[4] = __float2bfloat16(v.x); r.h[5] = __float2bfloat16(v.y);
    r.h[6] = __float2bfloat16(v.z); r.h[7] = __float2bfloat16(v.w);
    return r.f;
}

// ---- fused prep: adjacency build + W cast + A cast ------------------------
// ligand side stores EDGE ID (post_l derives dst via edge_dst[e]);
// target side stores SRC ID (post_t gathers x_ligand rows).
__global__ void prep(const int* __restrict__ src, const int* __restrict__ dst,
                     int* __restrict__ cur_l, int* __restrict__ cur_t,
                     int* __restrict__ adje, int* __restrict__ adjs, int E, int nb_fill,
                     const float* __restrict__ Wl, const float* __restrict__ Wr,
                     __hip_bfloat16* __restrict__ Wt, int nw, int nb_cast,
                     const float* __restrict__ Xt, __hip_bfloat16* __restrict__ Xb,
                     int nA8)
{
    int b = blockIdx.x;
    if (b < nb_fill) {
        int e = b * blockDim.x + threadIdx.x;
        if (e >= E) return;
        int s = src[e], d = dst[e];
        int p = atomicAdd(&cur_l[s], 1);
        adje[s * CAP_L + p] = e;
        int q = atomicAdd(&cur_t[d], 1);
        adjs[d * CAP_T + q] = s;
    } else if (b < nb_fill + nb_cast) {
        int idx = (b - nb_fill) * blockDim.x + threadIdx.x;
        if (idx >= nw) return;
        int nr = idx / K_DIM, k = idx - nr * K_DIM;
        float v = (nr < H) ? Wl[k * H + nr] : Wr[k * H + (nr - H)];
        Wt[idx] = __float2bfloat16(v);
    } else {
        // stream-cast x_target: 8 f32 -> bf16x8 per thread
        int g = (b - nb_fill - nb_cast) * blockDim.x + threadIdx.x;
        if (g >= nA8) return;
        const float4* s4 = (const float4*)Xt + (size_t)g * 2;
        float4 u = s4[0], v = s4[1];
        *(bf16x8*)((unsigned short*)Xb + (size_t)g * 8) = cvt8(u, v);
    }
}

// ---- GEMM: [M,1280] bf16 @ [1280,256] bf16 -> y_tl | t_lin (f32) ----------
__global__ __launch_bounds__(256)
void gemm_fused(const unsigned short* __restrict__ Xb,  // [M,1280] bf16
                const unsigned short* __restrict__ Wt,  // [256,1280] bf16 n-major
                float* __restrict__ y_tl, float* __restrict__ t_lin, int M)
{
    __shared__ short As[64 * 64];   //  8 KB; 16B-slot = m*8 + (c ^ (m&7))
    __shared__ short Bs[128 * 64];  // 16 KB; 16B-slot = n*8 + (c ^ (n&7))

    const int t = threadIdx.x;
    const int w = t >> 6, lane = t & 63;
    const int m16 = lane & 15, q = lane >> 4;
    const int wm = w & 1, wn = w >> 1;          // 2x2 wave grid
    const int mb = blockIdx.x >> 1, nb = blockIdx.x & 1;
    const int bm = mb * 64;
    const int nb128 = nb * 128;

    // ---- staging address setup (per-lane swizzled global source) ----
    // A: 512 slots (64 rows x 8 chunks of 16B); 2 DMA instrs/wave/chunk
    const unsigned short* a_g[2];
#pragma unroll
    for (int i = 0; i < 2; ++i) {
        int slot = i * 256 + w * 64 + lane;
        int m = slot >> 3, cl = slot & 7;
        int cg = cl ^ (m & 7);
        int row = min(bm + m, M - 1);
        a_g[i] = Xb + (size_t)row * K_DIM + cg * 8;
    }
    // B: 1024 slots (128 rows x 8 chunks of 16B); 4 DMA instrs/wave/chunk
    const unsigned short* b_g[4];
#pragma unroll
    for (int i = 0; i < 4; ++i) {
        int slot = i * 256 + w * 64 + lane;
        int n = slot >> 3, cl = slot & 7;
        int cg = cl ^ (n & 7);
        b_g[i] = Wt + (size_t)(nb128 + n) * K_DIM + cg * 8;
    }

    f32x4 acc[2][4];
#pragma unroll
    for (int i = 0; i < 2; ++i)
#pragma unroll
        for (int j = 0; j < 4; ++j)
            acc[i][j] = (f32x4){0.f, 0.f, 0.f, 0.f};

    // ---- stage chunk 0 ----
#pragma unroll
    for (int i = 0; i < 2; ++i)
        __builtin_amdgcn_global_load_lds(AS1(a_g[i]), AS3((char*)As + (i * 256 + w * 64) * 16), 16, 0, 0);
#pragma unroll
    for (int i = 0; i < 4; ++i)
        __builtin_amdgcn_global_load_lds(AS1(b_g[i]), AS3((char*)Bs + (i * 256 + w * 64) * 16), 16, 0, 0);
    __syncthreads();

    for (int ch = 0; ch < NCH; ++ch) {
        // compute chunk ch (2 k-steps of 32)
#pragma unroll
        for (int ks = 0; ks < 2; ++ks) {
            bf16x8 aF[2];
#pragma unroll
            for (int i = 0; i < 2; ++i) {
                int row = wm * 32 + i * 16 + m16;
                int c = ks * 4 + q;                   // 0..7
                int s = row * 8 + (c ^ (row & 7));
                aF[i] = *(const bf16x8*)((const char*)As + s * 16);
            }
            bf16x8 bF[4];
#pragma unroll
            for (int j = 0; j < 4; ++j) {
                int n = wn * 64 + j * 16 + m16;
                int c = ks * 4 + q;
                int s = n * 8 + (c ^ (n & 7));
                bF[j] = *(const bf16x8*)((const char*)Bs + s * 16);
            }
#pragma unroll
            for (int i = 0; i < 2; ++i)
#pragma unroll
                for (int j = 0; j < 4; ++j)
                    acc[i][j] = __builtin_amdgcn_mfma_f32_16x16x32_bf16(aF[i], bF[j], acc[i][j], 0, 0, 0);
        }
        __syncthreads();                    // done reading chunk ch
        if (ch + 1 < NCH) {
            const int kc = (ch + 1) * 64;   // offset in bf16 elements
#pragma unroll
            for (int i = 0; i < 2; ++i)
                __builtin_amdgcn_global_load_lds(AS1(a_g[i] + kc),
                                                 AS3((char*)As + (i * 256 + w * 64) * 16), 16, 0, 0);
#pragma unroll
            for (int i = 0; i < 4; ++i)
                __builtin_amdgcn_global_load_lds(AS1(b_g[i] + kc),
                                                 AS3((char*)Bs + (i * 256 + w * 64) * 16), 16, 0, 0);
            __syncthreads();                // publish chunk ch+1
        }
    }

    // ---- epilogue: row = bm + wm*32 + i*16 + q*4 + r; col = wn*64 + j*16 + m16
    float* __restrict__ Y = nb ? t_lin : y_tl;
#pragma unroll
    for (int i = 0; i < 2; ++i) {
#pragma unroll
        for (int j = 0; j < 4; ++j) {
            int col = wn * 64 + j * 16 + m16;
#pragma unroll
            for (int r = 0; r < 4; ++r) {
                int row = bm + wm * 32 + i * 16 + q * 4 + r;
                if (row < M) Y[(size_t)row * H + col] = acc[i][j][r];
            }
        }
    }
}

// ---- target post (wave per target): gather agg + linear + relu + dot ------
// st[wid] gets b_ep folded in so post_l's edge write is just sl + st[d].
__global__ void post_t(const int* __restrict__ cur_t, const int* __restrict__ adjs,
                       const float* __restrict__ xl, const float* __restrict__ t_lin,
                       const float* __restrict__ W_lt_l, const float* __restrict__ b_lt_l,
                       const float* __restrict__ W_ep, const float* __restrict__ b_ep,
                       float* __restrict__ st, int NT)
{
    int wid = (blockIdx.x * blockDim.x + threadIdx.x) >> 6;
    int lane = threadIdx.x & 63;
    if (wid >= NT) return;
    int cnt = cur_t[wid];
    float a0 = 0.f, a1 = 0.f, a2 = 0.f, a3 = 0.f;
    for (int j = lane; j < cnt; j += 64) {
        int s = adjs[wid * CAP_T + j];
        float4 v = *(const float4*)(xl + (size_t)s * LIG_IN);
        a0 += v.x; a1 += v.y; a2 += v.z; a3 += v.w;
    }
#pragma unroll
    for (int off = 32; off > 0; off >>= 1) {
        a0 += __shfl_xor(a0, off);
        a1 += __shfl_xor(a1, off);
        a2 += __shfl_xor(a2, off);
        a3 += __shfl_xor(a3, off);
    }
    float inv = 1.0f / fmaxf((float)cnt, 1.0f);
    a0 *= inv; a1 *= inv; a2 *= inv; a3 *= inv;
    float acc = 0.f;
#pragma unroll
    for (int p = 0; p < 2; ++p) {
        int h = lane + p * 64;
        float v = a0 * W_lt_l[h] + a1 * W_lt_l[H + h] + a2 * W_lt_l[2 * H + h] +
                  a3 * W_lt_l[3 * H + h] + b_lt_l[h] + t_lin[(size_t)wid * H + h];
        v = fmaxf(v, 0.f);
        acc += v * W_ep[H + h];
    }
#pragma unroll
    for (int off = 32; off > 0; off >>= 1) acc += __shfl_down(acc, off);
    if (lane == 0) st[wid] = acc + b_ep[0];
}

// ---- ligand post + edge write (wave per ligand) ---------------------------
__global__ void post_l(const int* __restrict__ cur_l, const int* __restrict__ adje,
                       const int* __restrict__ edge_dst,
                       const float* __restrict__ y_tl, const float* __restrict__ xl,
                       const float* __restrict__ W_tl_r, const float* __restrict__ b_tl_l,
                       const float* __restrict__ W_ep, const float* __restrict__ st,
                       float* __restrict__ out, int NL)
{
    int wid = (blockIdx.x * blockDim.x + threadIdx.x) >> 6;
    int lane = threadIdx.x & 63;
    if (wid >= NL) return;
    int cnt = cur_l[wid];
    int e = 0, d = 0;
    if (lane < cnt) {
        e = adje[wid * CAP_L + lane];   // coalesced
        d = edge_dst[e];                // one gather instr for the wave
    }
    float a0 = 0.f, a1 = 0.f;   // h = 2*lane, 2*lane+1
    for (int j = 0; j < cnt; ++j) {
        int dj = __shfl(d, j);
        float2 f = ((const float2*)(y_tl + (size_t)dj * H))[lane];  // 512B row load
        a0 += f.x;
        a1 += f.y;
    }
    float inv = 1.0f / fmaxf((float)cnt, 1.0f);
    float4 x = *(const float4*)(xl + (size_t)wid * LIG_IN);
    float acc = 0.f;
    {
        int h = 2 * lane;
        float v = a0 * inv + b_tl_l[h] +
                  x.x * W_tl_r[h] + x.y * W_tl_r[H + h] +
                  x.z * W_tl_r[2 * H + h] + x.w * W_tl_r[3 * H + h];
        v = fmaxf(v, 0.f);
        acc += v * W_ep[h];
    }
    {
        int h = 2 * lane + 1;
        float v = a1 * inv + b_tl_l[h] +
                  x.x * W_tl_r[h] + x.y * W_tl_r[H + h] +
                  x.z * W_tl_r[2 * H + h] + x.w * W_tl_r[3 * H + h];
        v = fmaxf(v, 0.f);
        acc += v * W_ep[h];
    }
#pragma unroll
    for (int off = 32; off > 0; off >>= 1) acc += __shfl_xor(acc, off);  // all lanes
    if (lane < cnt) out[e] = acc + st[d];
}

// ---------------------------------------------------------------------------
extern "C" void kernel_launch(void* const* d_in, const int* in_sizes, int n_in,
                              void* d_out, int out_size, void* d_ws, size_t ws_size,
                              hipStream_t stream) {
    const float* x_ligand = (const float*)d_in[0];
    const float* x_target = (const float*)d_in[1];
    const int*   edge_src = (const int*)d_in[2];
    const int*   edge_dst = (const int*)d_in[3];
    const float* W_lt_l   = (const float*)d_in[4];
    const float* b_lt_l   = (const float*)d_in[5];
    const float* W_lt_r   = (const float*)d_in[6];
    const float* W_tl_l   = (const float*)d_in[7];
    const float* b_tl_l   = (const float*)d_in[8];
    const float* W_tl_r   = (const float*)d_in[9];
    const float* W_ep     = (const float*)d_in[10];
    const float* b_ep     = (const float*)d_in[11];
    float* out = (float*)d_out;

    const int NL = in_sizes[0] / LIG_IN;   // 100000
    const int NT = in_sizes[1] / K_DIM;    // 20000
    const int E  = in_sizes[2];            // 250000

    // ---- workspace layout (16B-aligned offsets) ----
    char* ws = (char*)d_ws;
    size_t off = 0;
    auto take = [&](size_t bytes) { size_t o = off; off += (bytes + 15) & ~(size_t)15; return o; };
    size_t off_Wt     = take((size_t)2 * H * K_DIM * 2); // 655 KB bf16
    size_t off_Xb     = take((size_t)NT * K_DIM * 2);    // 51.2 MB bf16 A
    size_t off_y_tl   = take((size_t)NT * H * 4);        // 10.24 MB
    size_t off_t_lin  = take((size_t)NT * H * 4);        // 10.24 MB
    size_t off_adje   = take((size_t)NL * CAP_L * 4);    // 9.6 MB
    size_t off_adjs   = take((size_t)NT * CAP_T * 4);    // 3.84 MB
    size_t off_cur_l  = take((size_t)NL * 4);            // <- memset start
    size_t off_cur_t  = take((size_t)NT * 4);            // <- memset end
    size_t off_st     = take((size_t)NT * 4);
    if (off > ws_size) {
        hipMemsetAsync(d_out, 0, (size_t)out_size * 4, stream);
        return;
    }

    __hip_bfloat16* Wt = (__hip_bfloat16*)(ws + off_Wt);
    __hip_bfloat16* Xb = (__hip_bfloat16*)(ws + off_Xb);
    float* y_tl  = (float*)(ws + off_y_tl);
    float* t_lin = (float*)(ws + off_t_lin);
    int*   adje  = (int*)(ws + off_adje);
    int*   adjs  = (int*)(ws + off_adjs);
    int*   cur_l = (int*)(ws + off_cur_l);
    int*   cur_t = (int*)(ws + off_cur_t);
    float* st    = (float*)(ws + off_st);

    // zero the cursors (contiguous)
    hipMemsetAsync(cur_l, 0, off_st - off_cur_l, stream);

    // 1. fused adjacency build + weight cast + A cast
    int nw = 2 * H * K_DIM;
    int nA8 = NT * K_DIM / 8;              // 8-elem groups of x_target
    int nb_fill  = (E + 255) / 256;
    int nb_cast  = (nw + 255) / 256;
    int nb_castA = (nA8 + 255) / 256;
    prep<<<nb_fill + nb_cast + nb_castA, 256, 0, stream>>>(
        edge_src, edge_dst, cur_l, cur_t, adje, adjs, E, nb_fill,
        W_tl_l, W_lt_r, Wt, nw, nb_cast, x_target, Xb, nA8);

    // 2. GEMM: grid 626 (mb = bid>>1, nb = bid&1) — R12 structure, bf16 A
    gemm_fused<<<((NT + 63) / 64) * 2, 256, 0, stream>>>(
        (const unsigned short*)Xb, (const unsigned short*)Wt, y_tl, t_lin, NT);

    // 3. target post -> st (+ b_ep folded)
    post_t<<<(NT * 64 + 255) / 256, 256, 0, stream>>>(cur_t, adjs, x_ligand, t_lin,
                                                      W_lt_l, b_lt_l, W_ep, b_ep, st, NT);

    // 4. ligand post + edge write -> out
    post_l<<<(NL * 64 + 255) / 256, 256, 0, stream>>>(cur_l, adje, edge_dst, y_tl, x_ligand,
                                                      W_tl_r, b_tl_l, W_ep, st, out, NL);
}